// Round 1
// baseline (648.388 us; speedup 1.0000x reference)
//
#include <hip/hip_runtime.h>
#include <hip/hip_bf16.h>
#include <math.h>

#define N_NODES 50000
#define IN_CH   128
#define HID     64
#define HEADS   4
#define OUT_CH  16
#define NE      800000
#define ETOT    (NE + N_NODES)
#define NEG_SLOPE 0.2f

// ---------------------------------------------------------------------------
// GEMM1: xlxr1[n][m] = sum_k x[n][k] * Wcat[k][m],  Wcat = [W1l | W1r], m<512
// tile: 64 rows x 64 cols, K=128 staged fully. LDS ~66KB -> 2 blocks/CU.
// ---------------------------------------------------------------------------
__global__ __launch_bounds__(256) void k_gemm1(const float* __restrict__ x,
        const float* __restrict__ Wl, const float* __restrict__ Wr,
        float* __restrict__ out) {
    __shared__ float xs[64][132];   // 132 pad: banks spread, float4-aligned rows
    __shared__ float ws[128][64];
    int rb = blockIdx.x * 64;
    int cb = blockIdx.y * 64;                   // 0..448
    const float* W = (cb < 256) ? Wl : Wr;
    int wc = cb & 255;
    int tid = threadIdx.x;
    // stage x tile: 64 rows x 128 cols (2048 float4)
    for (int i = 0; i < 8; ++i) {
        int idx = i * 256 + tid;
        int r = idx >> 5;            // 32 float4 per row
        int c4 = idx & 31;
        float4 v = make_float4(0.f, 0.f, 0.f, 0.f);
        int gr = rb + r;
        if (gr < N_NODES) v = *(const float4*)(x + (size_t)gr * IN_CH + c4 * 4);
        *(float4*)&xs[r][c4 * 4] = v;
    }
    // stage W tile: 128 rows x 64 cols (2048 float4)
    for (int i = 0; i < 8; ++i) {
        int idx = i * 256 + tid;
        int r = idx >> 4;            // 16 float4 per row
        int c4 = idx & 15;
        *(float4*)&ws[r][c4 * 4] = *(const float4*)(W + (size_t)r * 256 + wc + c4 * 4);
    }
    __syncthreads();
    int cg = tid & 15, rg = tid >> 4;
    int c0 = cg * 4, r0 = rg * 4;
    float acc[4][4];
    #pragma unroll
    for (int i = 0; i < 4; ++i)
        #pragma unroll
        for (int j = 0; j < 4; ++j) acc[i][j] = 0.f;
    for (int k = 0; k < 128; ++k) {
        float xv[4];
        #pragma unroll
        for (int i = 0; i < 4; ++i) xv[i] = xs[r0 + i][k];
        float4 wv = *(float4*)&ws[k][c0];
        #pragma unroll
        for (int i = 0; i < 4; ++i) {
            acc[i][0] += xv[i] * wv.x;
            acc[i][1] += xv[i] * wv.y;
            acc[i][2] += xv[i] * wv.z;
            acc[i][3] += xv[i] * wv.w;
        }
    }
    #pragma unroll
    for (int i = 0; i < 4; ++i) {
        int gr = rb + r0 + i;
        if (gr < N_NODES) {
            float4 v = make_float4(acc[i][0], acc[i][1], acc[i][2], acc[i][3]);
            *(float4*)(out + (size_t)gr * 512 + cb + c0) = v;
        }
    }
}

// ---------------------------------------------------------------------------
// CSR build (bucket by dst). counts -> exclusive scan -> fill with src ids.
// ---------------------------------------------------------------------------
__global__ void k_count(const int* __restrict__ ei, int* __restrict__ counts) {
    int e = blockIdx.x * blockDim.x + threadIdx.x;
    if (e >= ETOT) return;
    int dst = (e < NE) ? ei[NE + e] : (e - NE);
    atomicAdd(&counts[dst], 1);
}

__global__ __launch_bounds__(256) void k_scanA(const int* __restrict__ counts,
        int* __restrict__ tmp, int* __restrict__ bsums) {
    __shared__ int lds[256];
    int i = blockIdx.x * 256 + threadIdx.x;
    int v = (i < N_NODES) ? counts[i] : 0;
    lds[threadIdx.x] = v;
    __syncthreads();
    int val = v;
    for (int off = 1; off < 256; off <<= 1) {
        int t = (threadIdx.x >= off) ? lds[threadIdx.x - off] : 0;
        __syncthreads();
        val += t;
        lds[threadIdx.x] = val;
        __syncthreads();
    }
    if (i < N_NODES) tmp[i] = val;               // inclusive within block
    if (threadIdx.x == 255) bsums[blockIdx.x] = val;
}

__global__ __launch_bounds__(256) void k_scanB(const int* __restrict__ bsums,
        int* __restrict__ boff, int nb) {
    __shared__ int lds[256];
    int tid = threadIdx.x;
    int v = (tid < nb) ? bsums[tid] : 0;
    lds[tid] = v;
    __syncthreads();
    int val = v;
    for (int off = 1; off < 256; off <<= 1) {
        int t = (tid >= off) ? lds[tid - off] : 0;
        __syncthreads();
        val += t;
        lds[tid] = val;
        __syncthreads();
    }
    if (tid < nb) boff[tid] = val - v;           // exclusive
}

__global__ void k_scanC(const int* __restrict__ tmp, const int* __restrict__ counts,
        const int* __restrict__ boff, int* __restrict__ rowptr, int* __restrict__ cursor) {
    int i = blockIdx.x * 256 + threadIdx.x;
    if (i >= N_NODES) return;
    int ex = tmp[i] + boff[blockIdx.x] - counts[i];   // exclusive prefix
    rowptr[i] = ex;
    cursor[i] = ex;
    if (i == N_NODES - 1) rowptr[N_NODES] = ex + counts[i];
}

__global__ void k_fill(const int* __restrict__ ei, int* __restrict__ cursor,
        int* __restrict__ csrc) {
    int e = blockIdx.x * blockDim.x + threadIdx.x;
    if (e >= ETOT) return;
    int src, dst;
    if (e < NE) { src = ei[e]; dst = ei[NE + e]; }
    else        { src = e - NE; dst = src; }
    int pos = atomicAdd(&cursor[dst], 1);
    csrc[pos] = src;
}

// ---------------------------------------------------------------------------
// Layer-1 aggregation: one wave per dst. lane=channel(64), 4 heads in regs.
// Inline logits (wave butterfly reduce) + online softmax + fused bias+ELU.
// ---------------------------------------------------------------------------
__global__ __launch_bounds__(256) void k_agg1(const float* __restrict__ xlxr,
        const int* __restrict__ rowptr, const int* __restrict__ csrc,
        const float* __restrict__ att, const float* __restrict__ b1,
        float* __restrict__ h) {
    int wave = threadIdx.x >> 6;
    int lane = threadIdx.x & 63;
    int d = blockIdx.x * 4 + wave;
    if (d >= N_NODES) return;
    float xr[4], av[4], m[4], s[4], acc[4];
    #pragma unroll
    for (int hh = 0; hh < 4; ++hh) {
        xr[hh]  = xlxr[(size_t)d * 512 + 256 + hh * 64 + lane];
        av[hh]  = att[hh * 64 + lane];
        m[hh]   = -INFINITY;
        s[hh]   = 0.f;
        acc[hh] = 0.f;
    }
    int e0 = rowptr[d], e1 = rowptr[d + 1];
    for (int i = e0; i < e1; ++i) {
        int src = csrc[i];
        float xl[4], t[4];
        #pragma unroll
        for (int hh = 0; hh < 4; ++hh) {
            xl[hh] = xlxr[(size_t)src * 512 + hh * 64 + lane];
            float u = xl[hh] + xr[hh];
            u = (u > 0.f) ? u : u * NEG_SLOPE;
            t[hh] = u * av[hh];
        }
        #pragma unroll
        for (int off = 32; off >= 1; off >>= 1) {
            #pragma unroll
            for (int hh = 0; hh < 4; ++hh) t[hh] += __shfl_xor(t[hh], off, 64);
        }
        #pragma unroll
        for (int hh = 0; hh < 4; ++hh) {
            float l  = t[hh];
            float nm = fmaxf(m[hh], l);
            float sc = __expf(m[hh] - nm);
            float p  = __expf(l - nm);
            s[hh]   = s[hh] * sc + p;
            acc[hh] = acc[hh] * sc + p * xl[hh];
            m[hh]   = nm;
        }
    }
    #pragma unroll
    for (int hh = 0; hh < 4; ++hh) {
        float v = acc[hh] / s[hh] + b1[hh * 64 + lane];
        v = (v > 0.f) ? v : (__expf(v) - 1.f);   // ELU fused
        h[(size_t)d * 256 + hh * 64 + lane] = v;
    }
}

// ---------------------------------------------------------------------------
// GEMM2: xlxr2[n][m] = sum_k h[n][k]*W2cat[k][m], m<32 ([W2l|W2r] cols 16+16)
// wave-per-node matvec; W2cat (32KB) staged in LDS.
// ---------------------------------------------------------------------------
__global__ __launch_bounds__(256) void k_gemm2(const float* __restrict__ h,
        const float* __restrict__ W2l, const float* __restrict__ W2r,
        float* __restrict__ out) {
    __shared__ float ws[256 * 32];
    int tid = threadIdx.x;
    for (int i = 0; i < 32; ++i) {
        int idx = i * 256 + tid;
        int k = idx >> 5, mm = idx & 31;
        ws[idx] = (mm < 16) ? W2l[k * 16 + mm] : W2r[k * 16 + (mm - 16)];
    }
    __syncthreads();
    int wave = tid >> 6, lane = tid & 63;
    int n = blockIdx.x * 4 + wave;
    if (n >= N_NODES) return;
    int mm = lane & 31, kh = lane >> 5;
    float acc = 0.f;
    const float* hp = h + (size_t)n * 256 + kh * 128;
    #pragma unroll
    for (int kk4 = 0; kk4 < 32; ++kk4) {
        float4 hv = *(const float4*)(hp + kk4 * 4);
        int kb = (kh * 128 + kk4 * 4) * 32 + mm;
        acc += hv.x * ws[kb] + hv.y * ws[kb + 32] + hv.z * ws[kb + 64] + hv.w * ws[kb + 96];
    }
    acc += __shfl_xor(acc, 32, 64);
    if (lane < 32) out[(size_t)n * 32 + mm] = acc;
}

// ---------------------------------------------------------------------------
// Layer-2 aggregation: wave per dst, 16 channels (4 redundant 16-lane groups).
// ---------------------------------------------------------------------------
__global__ __launch_bounds__(256) void k_agg2(const float* __restrict__ xlxr2,
        const int* __restrict__ rowptr, const int* __restrict__ csrc,
        const float* __restrict__ att2, const float* __restrict__ b2,
        float* __restrict__ out) {
    int wave = threadIdx.x >> 6, lane = threadIdx.x & 63;
    int d = blockIdx.x * 4 + wave;
    if (d >= N_NODES) return;
    int c = lane & 15;
    float xrv = xlxr2[(size_t)d * 32 + 16 + c];
    float a   = att2[c];
    float m = -INFINITY, s = 0.f, acc = 0.f;
    int e0 = rowptr[d], e1 = rowptr[d + 1];
    for (int i = e0; i < e1; ++i) {
        int src = csrc[i];
        float xl = xlxr2[(size_t)src * 32 + c];
        float u = xl + xrv;
        u = (u > 0.f) ? u : u * NEG_SLOPE;
        float t = u * a;
        t += __shfl_xor(t, 8, 64);
        t += __shfl_xor(t, 4, 64);
        t += __shfl_xor(t, 2, 64);
        t += __shfl_xor(t, 1, 64);
        float nm = fmaxf(m, t);
        float sc = __expf(m - nm), p = __expf(t - nm);
        s = s * sc + p;
        acc = acc * sc + p * xl;
        m = nm;
    }
    if (lane < 16) out[(size_t)d * 16 + c] = acc / s + b2[c];
}

// ---------------------------------------------------------------------------
extern "C" void kernel_launch(void* const* d_in, const int* in_sizes, int n_in,
                              void* d_out, int out_size, void* d_ws, size_t ws_size,
                              hipStream_t stream) {
    const float* x    = (const float*)d_in[0];
    const int*   ei   = (const int*)d_in[1];
    const float* W1l  = (const float*)d_in[2];
    const float* W1r  = (const float*)d_in[3];
    const float* att1 = (const float*)d_in[4];
    const float* b1   = (const float*)d_in[5];
    const float* W2l  = (const float*)d_in[6];
    const float* W2r  = (const float*)d_in[7];
    const float* att2 = (const float*)d_in[8];
    const float* b2   = (const float*)d_in[9];
    float* outp = (float*)d_out;

    char* wsb = (char*)d_ws;
    size_t off = 0;
    auto alloc = [&](size_t bytes) {
        void* p = wsb + off;
        off = (off + bytes + 255) & ~(size_t)255;
        return p;
    };
    float* xlxr1 = (float*)alloc((size_t)N_NODES * 512 * 4);  // 102.4 MB
    float* h1    = (float*)alloc((size_t)N_NODES * 256 * 4);  //  51.2 MB
    float* xlxr2 = (float*)alloc((size_t)N_NODES * 32 * 4);   //   6.4 MB
    int* rowptr  = (int*)alloc((N_NODES + 1) * 4);
    int* cursor  = (int*)alloc(N_NODES * 4);
    int* counts  = (int*)alloc(N_NODES * 4);
    int* tmp     = (int*)alloc(N_NODES * 4);
    int* bsums   = (int*)alloc(256 * 4);
    int* boff    = (int*)alloc(256 * 4);
    int* csrc    = (int*)alloc((size_t)ETOT * 4);             //   3.4 MB

    hipMemsetAsync(counts, 0, N_NODES * 4, stream);

    dim3 g1((N_NODES + 63) / 64, 8);
    k_gemm1<<<g1, 256, 0, stream>>>(x, W1l, W1r, xlxr1);

    int nb = (N_NODES + 255) / 256;
    k_count<<<(ETOT + 255) / 256, 256, 0, stream>>>(ei, counts);
    k_scanA<<<nb, 256, 0, stream>>>(counts, tmp, bsums);
    k_scanB<<<1, 256, 0, stream>>>(bsums, boff, nb);
    k_scanC<<<nb, 256, 0, stream>>>(tmp, counts, boff, rowptr, cursor);
    k_fill<<<(ETOT + 255) / 256, 256, 0, stream>>>(ei, cursor, csrc);

    k_agg1<<<(N_NODES + 3) / 4, 256, 0, stream>>>(xlxr1, rowptr, csrc, att1, b1, h1);
    k_gemm2<<<(N_NODES + 3) / 4, 256, 0, stream>>>(h1, W2l, W2r, xlxr2);
    k_agg2<<<(N_NODES + 3) / 4, 256, 0, stream>>>(xlxr2, rowptr, csrc, att2, b2, outp);
}

// Round 4
// 499.483 us; speedup vs baseline: 1.2981x; 1.2981x over previous
//
#include <hip/hip_runtime.h>
#include <hip/hip_bf16.h>
#include <math.h>

#define N_NODES 50000
#define IN_CH   128
#define HID     64
#define HEADS   4
#define OUT_CH  16
#define NE      800000
#define ETOT    (NE + N_NODES)
#define NEG_SLOPE 0.2f

// ---------------------------------------------------------------------------
// GEMM1: xlxr1[n][m] = sum_k x[n][k] * Wcat[k][m],  Wcat = [W1l | W1r], m<512
// ---------------------------------------------------------------------------
__global__ __launch_bounds__(256) void k_gemm1(const float* __restrict__ x,
        const float* __restrict__ Wl, const float* __restrict__ Wr,
        float* __restrict__ out) {
    __shared__ float xs[64][132];
    __shared__ float ws[128][64];
    int rb = blockIdx.x * 64;
    int cb = blockIdx.y * 64;
    const float* W = (cb < 256) ? Wl : Wr;
    int wc = cb & 255;
    int tid = threadIdx.x;
    for (int i = 0; i < 8; ++i) {
        int idx = i * 256 + tid;
        int r = idx >> 5, c4 = idx & 31;
        float4 v = make_float4(0.f, 0.f, 0.f, 0.f);
        int gr = rb + r;
        if (gr < N_NODES) v = *(const float4*)(x + (size_t)gr * IN_CH + c4 * 4);
        *(float4*)&xs[r][c4 * 4] = v;
    }
    for (int i = 0; i < 8; ++i) {
        int idx = i * 256 + tid;
        int r = idx >> 4, c4 = idx & 15;
        *(float4*)&ws[r][c4 * 4] = *(const float4*)(W + (size_t)r * 256 + wc + c4 * 4);
    }
    __syncthreads();
    int cg = tid & 15, rg = tid >> 4;
    int c0 = cg * 4, r0 = rg * 4;
    float acc[4][4];
    #pragma unroll
    for (int i = 0; i < 4; ++i)
        #pragma unroll
        for (int j = 0; j < 4; ++j) acc[i][j] = 0.f;
    for (int k = 0; k < 128; ++k) {
        float xv[4];
        #pragma unroll
        for (int i = 0; i < 4; ++i) xv[i] = xs[r0 + i][k];
        float4 wv = *(float4*)&ws[k][c0];
        #pragma unroll
        for (int i = 0; i < 4; ++i) {
            acc[i][0] += xv[i] * wv.x;
            acc[i][1] += xv[i] * wv.y;
            acc[i][2] += xv[i] * wv.z;
            acc[i][3] += xv[i] * wv.w;
        }
    }
    #pragma unroll
    for (int i = 0; i < 4; ++i) {
        int gr = rb + r0 + i;
        if (gr < N_NODES) {
            float4 v = make_float4(acc[i][0], acc[i][1], acc[i][2], acc[i][3]);
            *(float4*)(out + (size_t)gr * 512 + cb + c0) = v;
        }
    }
}

// ---------------------------------------------------------------------------
// CSR build (bucket by dst)
// ---------------------------------------------------------------------------
__global__ void k_count(const int* __restrict__ ei, int* __restrict__ counts) {
    int e = blockIdx.x * blockDim.x + threadIdx.x;
    if (e >= ETOT) return;
    int dst = (e < NE) ? ei[NE + e] : (e - NE);
    atomicAdd(&counts[dst], 1);
}

__global__ __launch_bounds__(256) void k_scanA(const int* __restrict__ counts,
        int* __restrict__ tmp, int* __restrict__ bsums) {
    __shared__ int lds[256];
    int i = blockIdx.x * 256 + threadIdx.x;
    int v = (i < N_NODES) ? counts[i] : 0;
    lds[threadIdx.x] = v;
    __syncthreads();
    int val = v;
    for (int off = 1; off < 256; off <<= 1) {
        int t = (threadIdx.x >= off) ? lds[threadIdx.x - off] : 0;
        __syncthreads();
        val += t;
        lds[threadIdx.x] = val;
        __syncthreads();
    }
    if (i < N_NODES) tmp[i] = val;
    if (threadIdx.x == 255) bsums[blockIdx.x] = val;
}

__global__ __launch_bounds__(256) void k_scanB(const int* __restrict__ bsums,
        int* __restrict__ boff, int nb) {
    __shared__ int lds[256];
    int tid = threadIdx.x;
    int v = (tid < nb) ? bsums[tid] : 0;
    lds[tid] = v;
    __syncthreads();
    int val = v;
    for (int off = 1; off < 256; off <<= 1) {
        int t = (tid >= off) ? lds[tid - off] : 0;
        __syncthreads();
        val += t;
        lds[tid] = val;
        __syncthreads();
    }
    if (tid < nb) boff[tid] = val - v;
}

__global__ void k_scanC(const int* __restrict__ tmp, const int* __restrict__ counts,
        const int* __restrict__ boff, int* __restrict__ rowptr, int* __restrict__ cursor) {
    int i = blockIdx.x * 256 + threadIdx.x;
    if (i >= N_NODES) return;
    int ex = tmp[i] + boff[blockIdx.x] - counts[i];
    rowptr[i] = ex;
    cursor[i] = ex;
    if (i == N_NODES - 1) rowptr[N_NODES] = ex + counts[i];
}

__global__ void k_fill(const int* __restrict__ ei, int* __restrict__ cursor,
        int* __restrict__ csrc) {
    int e = blockIdx.x * blockDim.x + threadIdx.x;
    if (e >= ETOT) return;
    int src, dst;
    if (e < NE) { src = ei[e]; dst = ei[NE + e]; }
    else        { src = e - NE; dst = src; }
    int pos = atomicAdd(&cursor[dst], 1);
    csrc[pos] = src;
}

// ---------------------------------------------------------------------------
// Layer-1 aggregation. lane -> (head = lane>>4, chans = (lane&15)*4 .. +3).
// One float4 gather per edge per lane (1KB/wave), 4-shuffle 16-lane reduce,
// one online-softmax chain per lane, fused bias+ELU.
// ---------------------------------------------------------------------------
__device__ __forceinline__ float edge_logit(float4 xl, float4 xr, float4 av) {
    float4 u;
    u.x = xl.x + xr.x; u.y = xl.y + xr.y; u.z = xl.z + xr.z; u.w = xl.w + xr.w;
    u.x = (u.x > 0.f) ? u.x : u.x * NEG_SLOPE;
    u.y = (u.y > 0.f) ? u.y : u.y * NEG_SLOPE;
    u.z = (u.z > 0.f) ? u.z : u.z * NEG_SLOPE;
    u.w = (u.w > 0.f) ? u.w : u.w * NEG_SLOPE;
    return u.x * av.x + u.y * av.y + u.z * av.z + u.w * av.w;
}

__global__ __launch_bounds__(256) void k_agg1(const float* __restrict__ xlxr,
        const int* __restrict__ rowptr, const int* __restrict__ csrc,
        const float* __restrict__ att, const float* __restrict__ b1,
        float* __restrict__ h) {
    int wave = threadIdx.x >> 6, lane = threadIdx.x & 63;
    int d = blockIdx.x * 4 + wave;
    if (d >= N_NODES) return;
    int hh = lane >> 4, cb = (lane & 15) * 4;
    int co = hh * 64 + cb;                       // channel offset within 256
    const float* base_l = xlxr + co;             // + src*512 -> xl chans
    float4 xr = *(const float4*)(xlxr + (size_t)d * 512 + 256 + co);
    float4 av = *(const float4*)(att + co);
    float m = -1e30f, s = 0.f;
    float4 acc = make_float4(0.f, 0.f, 0.f, 0.f);
    int e0 = rowptr[d], e1 = rowptr[d + 1];
    int i = e0;
    for (; i + 1 < e1; i += 2) {
        int s0 = csrc[i], s1 = csrc[i + 1];
        float4 x0 = *(const float4*)(base_l + (size_t)s0 * 512);
        float4 x1 = *(const float4*)(base_l + (size_t)s1 * 512);
        float t0 = edge_logit(x0, xr, av);
        float t1 = edge_logit(x1, xr, av);
        t0 += __shfl_xor(t0, 8, 64);  t1 += __shfl_xor(t1, 8, 64);
        t0 += __shfl_xor(t0, 4, 64);  t1 += __shfl_xor(t1, 4, 64);
        t0 += __shfl_xor(t0, 2, 64);  t1 += __shfl_xor(t1, 2, 64);
        t0 += __shfl_xor(t0, 1, 64);  t1 += __shfl_xor(t1, 1, 64);
        {
            float nm = fmaxf(m, t0);
            float sc = __expf(m - nm), p = __expf(t0 - nm);
            s = s * sc + p;
            acc.x = acc.x * sc + p * x0.x;
            acc.y = acc.y * sc + p * x0.y;
            acc.z = acc.z * sc + p * x0.z;
            acc.w = acc.w * sc + p * x0.w;
            m = nm;
        }
        {
            float nm = fmaxf(m, t1);
            float sc = __expf(m - nm), p = __expf(t1 - nm);
            s = s * sc + p;
            acc.x = acc.x * sc + p * x1.x;
            acc.y = acc.y * sc + p * x1.y;
            acc.z = acc.z * sc + p * x1.z;
            acc.w = acc.w * sc + p * x1.w;
            m = nm;
        }
    }
    if (i < e1) {
        int s0 = csrc[i];
        float4 x0 = *(const float4*)(base_l + (size_t)s0 * 512);
        float t0 = edge_logit(x0, xr, av);
        t0 += __shfl_xor(t0, 8, 64);
        t0 += __shfl_xor(t0, 4, 64);
        t0 += __shfl_xor(t0, 2, 64);
        t0 += __shfl_xor(t0, 1, 64);
        float nm = fmaxf(m, t0);
        float sc = __expf(m - nm), p = __expf(t0 - nm);
        s = s * sc + p;
        acc.x = acc.x * sc + p * x0.x;
        acc.y = acc.y * sc + p * x0.y;
        acc.z = acc.z * sc + p * x0.z;
        acc.w = acc.w * sc + p * x0.w;
        m = nm;
    }
    float inv = 1.f / s;
    float4 bv = *(const float4*)(b1 + co);
    float4 v;
    v.x = acc.x * inv + bv.x;
    v.y = acc.y * inv + bv.y;
    v.z = acc.z * inv + bv.z;
    v.w = acc.w * inv + bv.w;
    v.x = (v.x > 0.f) ? v.x : (__expf(v.x) - 1.f);
    v.y = (v.y > 0.f) ? v.y : (__expf(v.y) - 1.f);
    v.z = (v.z > 0.f) ? v.z : (__expf(v.z) - 1.f);
    v.w = (v.w > 0.f) ? v.w : (__expf(v.w) - 1.f);
    *(float4*)(h + (size_t)d * 256 + co) = v;
}

// ---------------------------------------------------------------------------
// GEMM2: W staged once per block; grid-stride loop over node groups.
// ---------------------------------------------------------------------------
__global__ __launch_bounds__(256) void k_gemm2(const float* __restrict__ h,
        const float* __restrict__ W2l, const float* __restrict__ W2r,
        float* __restrict__ out) {
    __shared__ float ws[256 * 32];
    int tid = threadIdx.x;
    for (int i = 0; i < 32; ++i) {
        int idx = i * 256 + tid;
        int k = idx >> 5, mm = idx & 31;
        ws[idx] = (mm < 16) ? W2l[k * 16 + mm] : W2r[k * 16 + (mm - 16)];
    }
    __syncthreads();
    int wave = tid >> 6, lane = tid & 63;
    int mm = lane & 31, kh = lane >> 5;
    for (int n = blockIdx.x * 4 + wave; n < N_NODES; n += gridDim.x * 4) {
        float acc = 0.f;
        const float* hp = h + (size_t)n * 256 + kh * 128;
        #pragma unroll
        for (int kk4 = 0; kk4 < 32; ++kk4) {
            float4 hv = *(const float4*)(hp + kk4 * 4);
            int kb = (kh * 128 + kk4 * 4) * 32 + mm;
            acc += hv.x * ws[kb] + hv.y * ws[kb + 32] + hv.z * ws[kb + 64] + hv.w * ws[kb + 96];
        }
        acc += __shfl_xor(acc, 32, 64);
        if (lane < 32) out[(size_t)n * 32 + mm] = acc;
    }
}

// ---------------------------------------------------------------------------
// Layer-2 aggregation: 4 edges per wave-iteration, 16 lanes each; merge the 4
// online-softmax partials at the end via xor-16/32 shuffles.
// ---------------------------------------------------------------------------
__global__ __launch_bounds__(256) void k_agg2(const float* __restrict__ xlxr2,
        const int* __restrict__ rowptr, const int* __restrict__ csrc,
        const float* __restrict__ att2, const float* __restrict__ b2,
        float* __restrict__ out) {
    int wave = threadIdx.x >> 6, lane = threadIdx.x & 63;
    int d = blockIdx.x * 4 + wave;
    if (d >= N_NODES) return;
    int g = lane >> 4, c = lane & 15;
    float xrv = xlxr2[(size_t)d * 32 + 16 + c];
    float a   = att2[c];
    float m = -1e30f, s = 0.f, acc = 0.f;
    int e0 = rowptr[d], e1 = rowptr[d + 1];
    for (int i = e0 + g; i < e1; i += 4) {
        int src = csrc[i];
        float xl = xlxr2[(size_t)src * 32 + c];
        float u = xl + xrv;
        u = (u > 0.f) ? u : u * NEG_SLOPE;
        float t = u * a;
        t += __shfl_xor(t, 8, 64);
        t += __shfl_xor(t, 4, 64);
        t += __shfl_xor(t, 2, 64);
        t += __shfl_xor(t, 1, 64);
        float nm = fmaxf(m, t);
        float sc = __expf(m - nm), p = __expf(t - nm);
        s = s * sc + p;
        acc = acc * sc + p * xl;
        m = nm;
    }
    #pragma unroll
    for (int off = 16; off <= 32; off <<= 1) {
        float mo = __shfl_xor(m, off, 64);
        float so = __shfl_xor(s, off, 64);
        float ao = __shfl_xor(acc, off, 64);
        float nm = fmaxf(m, mo);
        float ea = __expf(m - nm), eb = __expf(mo - nm);
        s   = s * ea + so * eb;
        acc = acc * ea + ao * eb;
        m = nm;
    }
    if (lane < 16) out[(size_t)d * 16 + c] = acc / s + b2[c];
}

// ---------------------------------------------------------------------------
extern "C" void kernel_launch(void* const* d_in, const int* in_sizes, int n_in,
                              void* d_out, int out_size, void* d_ws, size_t ws_size,
                              hipStream_t stream) {
    const float* x    = (const float*)d_in[0];
    const int*   ei   = (const int*)d_in[1];
    const float* W1l  = (const float*)d_in[2];
    const float* W1r  = (const float*)d_in[3];
    const float* att1 = (const float*)d_in[4];
    const float* b1   = (const float*)d_in[5];
    const float* W2l  = (const float*)d_in[6];
    const float* W2r  = (const float*)d_in[7];
    const float* att2 = (const float*)d_in[8];
    const float* b2   = (const float*)d_in[9];
    float* outp = (float*)d_out;

    char* wsb = (char*)d_ws;
    size_t off = 0;
    auto alloc = [&](size_t bytes) {
        void* p = wsb + off;
        off = (off + bytes + 255) & ~(size_t)255;
        return p;
    };
    float* xlxr1 = (float*)alloc((size_t)N_NODES * 512 * 4);
    float* h1    = (float*)alloc((size_t)N_NODES * 256 * 4);
    float* xlxr2 = (float*)alloc((size_t)N_NODES * 32 * 4);
    int* rowptr  = (int*)alloc((N_NODES + 1) * 4);
    int* cursor  = (int*)alloc(N_NODES * 4);
    int* counts  = (int*)alloc(N_NODES * 4);
    int* tmp     = (int*)alloc(N_NODES * 4);
    int* bsums   = (int*)alloc(256 * 4);
    int* boff    = (int*)alloc(256 * 4);
    int* csrc    = (int*)alloc((size_t)ETOT * 4);

    hipMemsetAsync(counts, 0, N_NODES * 4, stream);

    dim3 g1((N_NODES + 63) / 64, 8);
    k_gemm1<<<g1, 256, 0, stream>>>(x, W1l, W1r, xlxr1);

    int nb = (N_NODES + 255) / 256;
    k_count<<<(ETOT + 255) / 256, 256, 0, stream>>>(ei, counts);
    k_scanA<<<nb, 256, 0, stream>>>(counts, tmp, bsums);
    k_scanB<<<1, 256, 0, stream>>>(bsums, boff, nb);
    k_scanC<<<nb, 256, 0, stream>>>(tmp, counts, boff, rowptr, cursor);
    k_fill<<<(ETOT + 255) / 256, 256, 0, stream>>>(ei, cursor, csrc);

    k_agg1<<<(N_NODES + 3) / 4, 256, 0, stream>>>(xlxr1, rowptr, csrc, att1, b1, h1);
    k_gemm2<<<1280, 256, 0, stream>>>(h1, W2l, W2r, xlxr2);
    k_agg2<<<(N_NODES + 3) / 4, 256, 0, stream>>>(xlxr2, rowptr, csrc, att2, b2, outp);
}